// Round 10
// baseline (7255.540 us; speedup 1.0000x reference)
//
#include <hip/hip_runtime.h>
#include <math.h>

#define NDIM 64
#define PITCH 68          // chunk-row pitch in words: float4-aligned, conflict-free
#define KC 16             // columns staged per reconstruction chunk
#define MAXSWEEPS 20

// One wave per TWO 64x64 SPD matrices. Lane j owns column j of both matrices.
// One-sided (Hestenes) Jacobi, XOR pair ordering, alternating direction per sweep.
//
// Round-10: R1/R5/R7/R9 all land at 5.7ms with per-wave VALU duty ~14%, DS ~10%
// (75-80% stall), invariant under occupancy/DS-count/reordering changes; R8/R9
// proved the compiler normalizes any source-level pipeline back to stream-y2.
// Remaining hypotheses: (i) per-chain latency uncoverable by 2.5 waves/SIMD,
// (ii) DS-pipe saturation. This round separates them: TWO independent matrices
// per wave (xa,xb = 128 VGPRs state), every phase duplicated A/B. Independent
// chains let chain-B VALU issue under chain-A's bpermute waits — per-wave issue
// duty doubles with zero scheduling tricks. If (i): ~3-4ms, VALUBusy 50-65%.
// If (ii): flat ~5.7ms (DS demand/wave doubles, waves halve) -> DS confirmed.
// Structure is R5's verbatim (compiler's preferred stream-y schedule), just x2.
// Epilogue: A then B through the same wave-private LDS (program order, no
// barriers; single-wave blocks).
typedef float v2f __attribute__((ext_vector_type(2)));

__device__ __forceinline__ v2f pk_fma(v2f a, v2f b, v2f c)
{
    v2f d;
    asm("v_pk_fma_f32 %0, %1, %2, %3" : "=v"(d) : "v"(a), "v"(b), "v"(c));
    return d;
}

__device__ __forceinline__ v2f pk_mul(v2f a, v2f b)
{
    v2f d;
    asm("v_pk_mul_f32 %0, %1, %2" : "=v"(d) : "v"(a), "v"(b));
    return d;
}

__device__ __forceinline__ float bpermf(int pidx, float v)
{
    return __int_as_float(__builtin_amdgcn_ds_bpermute(pidx, __float_as_int(v)));
}

// division-free symmetric Schur (Golub-Van-Loan): from gamma and the pair's
// self-dots (aa=p's, bb=q's), produce rotation (C2,S2) and alpha increment TG.
// w,d identical on both lanes of a pair -> bitwise-same t,c,s on both lanes.
// 1e-35 floor keeps the w-denormal/d==0 corner finite; rot-select kills 0/0.
#define SCHUR(GAMMA, ALPHA, AEX, ISP, C2, S2, TG)                                \
    {                                                                            \
        const float aa  = (ISP) ? (ALPHA) : (AEX);                               \
        const float bb  = (ISP) ? (AEX) : (ALPHA);                               \
        any_big = any_big || ((GAMMA) * (GAMMA) > (1e-9f * aa * bb));            \
        const bool  rot = ((GAMMA) != 0.0f);                                     \
        const float w   = 2.0f * (GAMMA);                                        \
        const float d   = bb - aa;                                               \
        const float den = fabsf(d) + __builtin_amdgcn_sqrtf(fmaf(w, w, fmaf(d, d, 1e-35f))); \
        const float t   = ((d >= 0.0f) ? w : -w) * __builtin_amdgcn_rcpf(den);   \
        const float cc  = __builtin_amdgcn_rsqf(fmaf(t, t, 1.0f));               \
        const float ss  = t * cc;                                                \
        const float sgn = (ISP) ? -1.0f : 1.0f;                                  \
        const float c_r = rot ? cc : 1.0f;                                       \
        const float s_r = rot ? sgn * ss : 0.0f;                                 \
        (TG) = rot ? sgn * t * (GAMMA) : 0.0f;                                   \
        (C2).x = c_r; (C2).y = c_r;                                              \
        (S2).x = s_r; (S2).y = s_r;                                              \
    }

// chunked reconstruction of one matrix through the wave-private LDS buffers:
// O[:,lane] = sum_k w_k * m_{lane,k} * m_{:,k}. Wave-internal DS program order
// makes write->read safe with no barriers.
#define RECON(X2, OPTR)                                                          \
    {                                                                            \
        v2f acc2[NDIM / 2];                                                      \
        _Pragma("unroll")                                                        \
        for (int i = 0; i < NDIM / 2; ++i) { acc2[i].x = 0.f; acc2[i].y = 0.f; } \
        _Pragma("unroll 1")                                                      \
        for (int c = 0; c < NDIM; c += KC) {                                     \
            if (lane >= c && lane < c + KC) {                                    \
                float4* row = (float4*)&ldsM[(lane - c) * PITCH];                \
                _Pragma("unroll")                                                \
                for (int t4 = 0; t4 < NDIM / 4; ++t4)                            \
                    row[t4] = make_float4(X2[2 * t4].x, X2[2 * t4].y,            \
                                          X2[2 * t4 + 1].x, X2[2 * t4 + 1].y);   \
            }                                                                    \
            _Pragma("unroll 1")                                                  \
            for (int kk = 0; kk < KC; ++kk) {                                    \
                const float wk  = ldsW[c + kk];                                  \
                const float mlk = ldsM[kk * PITCH + lane];                       \
                const float zk  = wk * mlk;                                      \
                v2f zk2; zk2.x = zk; zk2.y = zk;                                 \
                const float4* rowk = (const float4*)&ldsM[kk * PITCH];           \
                _Pragma("unroll")                                                \
                for (int t4 = 0; t4 < NDIM / 4; ++t4) {                          \
                    const float4 v = rowk[t4];                                   \
                    v2f lo; lo.x = v.x; lo.y = v.y;                              \
                    v2f hi; hi.x = v.z; hi.y = v.w;                              \
                    acc2[2 * t4]     = pk_fma(zk2, lo, acc2[2 * t4]);            \
                    acc2[2 * t4 + 1] = pk_fma(zk2, hi, acc2[2 * t4 + 1]);        \
                }                                                                \
            }                                                                    \
        }                                                                        \
        _Pragma("unroll")                                                        \
        for (int i = 0; i < NDIM / 2; ++i) {                                     \
            (OPTR)[(2 * i + 0) * NDIM + lane] = acc2[i].x;                       \
            (OPTR)[(2 * i + 1) * NDIM + lane] = acc2[i].y;                       \
        }                                                                        \
    }

__global__ __launch_bounds__(64, 1)
void logeig_jacobi_kernel(const float* __restrict__ in, float* __restrict__ out)
{
    const int lane = threadIdx.x;
    const int b0   = blockIdx.x * 2;
    const float* A0 = in  + (size_t)b0 * (NDIM * NDIM);
    const float* A1 = A0 + NDIM * NDIM;
    float*       O0 = out + (size_t)b0 * (NDIM * NDIM);
    float*       O1 = O0 + NDIM * NDIM;

    __shared__ float ldsM[KC * PITCH];   // wave-private, reused A then B
    __shared__ float ldsW[NDIM];

    // stage in both matrices: column 'lane', 32 float2 pairs each; coalesced
    v2f xa[NDIM / 2], xb[NDIM / 2];
#pragma unroll
    for (int i = 0; i < NDIM / 2; ++i) {
        xa[i].x = A0[(2 * i + 0) * NDIM + lane];
        xa[i].y = A0[(2 * i + 1) * NDIM + lane];
        xb[i].x = A1[(2 * i + 0) * NDIM + lane];
        xb[i].y = A1[(2 * i + 1) * NDIM + lane];
    }

    float alA = 0.0f, alB = 0.0f;   // refreshed at each sweep start

#pragma unroll 1
    for (int sweep = 0; sweep < MAXSWEEPS; ++sweep) {
        // refresh self-dots (kills incremental-update drift); packed
        v2f ra0 = {0.f, 0.f}, ra1 = {0.f, 0.f}, rb0 = {0.f, 0.f}, rb1 = {0.f, 0.f};
#pragma unroll
        for (int i = 0; i < NDIM / 2; i += 2) {
            ra0 = pk_fma(xa[i],     xa[i],     ra0);
            ra1 = pk_fma(xa[i + 1], xa[i + 1], ra1);
            rb0 = pk_fma(xb[i],     xb[i],     rb0);
            rb1 = pk_fma(xb[i + 1], xb[i + 1], rb1);
        }
        alA = (ra0.x + ra0.y) + (ra1.x + ra1.y);
        alB = (rb0.x + rb0.y) + (rb1.x + rb1.y);

        bool any_big = false;   // combined over both matrices; one ballot/sweep
#pragma unroll 1
        for (int mi = 1; mi < NDIM; ++mi) {
            const int m    = (sweep & 1) ? (NDIM - mi) : mi;  // alternate direction
            const int pidx = (lane ^ m) << 2;

            // pull partner columns for BOTH matrices (independent DS streams)
            v2f ya[NDIM / 2], yb[NDIM / 2];
#pragma unroll
            for (int i = 0; i < NDIM / 2; ++i) {
                ya[i].x = bpermf(pidx, xa[i].x);
                ya[i].y = bpermf(pidx, xa[i].y);
                yb[i].x = bpermf(pidx, xb[i].x);
                yb[i].y = bpermf(pidx, xb[i].y);
            }

            // cross dots; product order identical on both lanes of a pair
            v2f ga0 = {0.f, 0.f}, ga1 = {0.f, 0.f}, gb0 = {0.f, 0.f}, gb1 = {0.f, 0.f};
#pragma unroll
            for (int i = 0; i < NDIM / 2; i += 2) {
                ga0 = pk_fma(xa[i],     ya[i],     ga0);
                ga1 = pk_fma(xa[i + 1], ya[i + 1], ga1);
                gb0 = pk_fma(xb[i],     yb[i],     gb0);
                gb1 = pk_fma(xb[i + 1], yb[i + 1], gb1);
            }
            const float gammaA = (ga0.x + ga0.y) + (ga1.x + ga1.y);
            const float gammaB = (gb0.x + gb0.y) + (gb1.x + gb1.y);

            const float aexA = bpermf(pidx, alA);
            const float aexB = bpermf(pidx, alB);
            const bool  is_p = lane < (lane ^ m);

            v2f c2a, s2a, c2b, s2b;
            float tgA, tgB;
            SCHUR(gammaA, alA, aexA, is_p, c2a, s2a, tgA)
            SCHUR(gammaB, alB, aexB, is_p, c2b, s2b, tgB)

#pragma unroll
            for (int i = 0; i < NDIM / 2; ++i) {
                xa[i] = pk_fma(c2a, xa[i], pk_mul(s2a, ya[i]));
                xb[i] = pk_fma(c2b, xb[i], pk_mul(s2b, yb[i]));
            }
            alA += tgA;
            alB += tgB;
        }
        if (__ballot(any_big) == 0ull) break;   // both matrices converged
    }

    // eigenvalues & weights, then reconstruct A and B sequentially through the
    // same wave-private LDS (program order; no barriers).
    v2f fa0 = {0.f, 0.f}, fa1 = {0.f, 0.f}, fb0 = {0.f, 0.f}, fb1 = {0.f, 0.f};
#pragma unroll
    for (int i = 0; i < NDIM / 2; i += 2) {
        fa0 = pk_fma(xa[i],     xa[i],     fa0);
        fa1 = pk_fma(xa[i + 1], xa[i + 1], fa1);
        fb0 = pk_fma(xb[i],     xb[i],     fb0);
        fb1 = pk_fma(xb[i + 1], xb[i + 1], fb1);
    }
    const float afA = (fa0.x + fa0.y) + (fa1.x + fa1.y);
    const float afB = (fb0.x + fb0.y) + (fb1.x + fb1.y);

    ldsW[lane] = logf(__builtin_amdgcn_sqrtf(afA) + 1e-9f) / afA;
    RECON(xa, O0)

    ldsW[lane] = logf(__builtin_amdgcn_sqrtf(afB) + 1e-9f) / afB;
    RECON(xb, O1)
}

extern "C" void kernel_launch(void* const* d_in, const int* in_sizes, int n_in,
                              void* d_out, int out_size, void* d_ws, size_t ws_size,
                              hipStream_t stream)
{
    const float* in  = (const float*)d_in[0];
    float*       out = (float*)d_out;
    const int nmat = out_size / (NDIM * NDIM);   // 256*32 = 8192
    hipLaunchKernelGGL(logeig_jacobi_kernel, dim3(nmat / 2), dim3(64), 0, stream, in, out);
}

// Round 11
// 5721.041 us; speedup vs baseline: 1.2682x; 1.2682x over previous
//
#include <hip/hip_runtime.h>
#include <math.h>

#define NDIM 64
#define NV   16           // v2f per half-column (32 rows per wave)
#define KC   16           // columns staged per reconstruction chunk
#define MAXSWEEPS 20

// TWO waves per 64x64 SPD matrix. Wave h owns rows [32h,32h+32) of all 64
// columns; lane j owns the half of column j. One-sided (Hestenes) Jacobi,
// XOR pair ordering, alternating direction per sweep.
//
// Round-11: ten rounds establish the kernel sits ON the DS-pipe throughput
// floor in the streaming regime (R5: 129 DS-instr/rot x 4.8cyc x 693 x 32/CU
// = 13.7M cyc == 13.8M measured), and that the pipe needs ~10 waves/CU to
// stay saturated (R6/R8/R10: fewer waves at high VGPR = slower, never faster).
// The bind: 129 instead of 65 DS/rot because y2 cannot stay live under the
// 85-VGPR cap that 10 waves/CU requires (x2 alone is 64 regs). Fix: halve
// per-lane state. With half-columns, x2=32 + y2=32 + temps ~ 80 regs: the
// partner HALF-column fits LIVE under the cap -> no refetch, 10 waves/CU kept.
// Cross-wave cost: gamma needs a 2-partial combine through LDS with ONE
// barrier per rotation (double-buffered slot; buffer k+2's reuse is fenced by
// barrier k+1). DS/rot/wave: 32 bperm(y) + 1 bperm(aex) + 1 write + 2 reads
// = 36; per matrix 72 vs 129 -> DS floor ~3.2ms.
// Bitwise parity: gamma = ldsG[lane]+ldsG[64+lane] in fixed order on both
// waves and both pair lanes; alpha/aex identical across halves -> identical
// Schur -> identical rotations -> uniform convergence ballot on both waves.
typedef float v2f __attribute__((ext_vector_type(2)));

__device__ __forceinline__ v2f pk_fma(v2f a, v2f b, v2f c)
{
    v2f d;
    asm("v_pk_fma_f32 %0, %1, %2, %3" : "=v"(d) : "v"(a), "v"(b), "v"(c));
    return d;
}

__device__ __forceinline__ v2f pk_mul(v2f a, v2f b)
{
    v2f d;
    asm("v_pk_mul_f32 %0, %1, %2" : "=v"(d) : "v"(a), "v"(b));
    return d;
}

__device__ __forceinline__ float bpermf(int pidx, float v)
{
    return __int_as_float(__builtin_amdgcn_ds_bpermute(pidx, __float_as_int(v)));
}

__global__ __launch_bounds__(128, 3)
void logeig_jacobi_kernel(const float* __restrict__ in, float* __restrict__ out)
{
    const int tid   = threadIdx.x;
    const int h     = tid >> 6;          // half: 0 = rows 0-31, 1 = rows 32-63
    const int lane  = tid & 63;          // column index
    const int rbase = h << 5;            // first row owned by this wave
    const int b     = blockIdx.x;
    const float* A  = in  + (size_t)b * (NDIM * NDIM);
    float*       O  = out + (size_t)b * (NDIM * NDIM);

    __shared__ float ldsG[2][2 * NDIM];  // double-buffered cross-wave partials
    __shared__ float ldsW[NDIM];         // per-column weights
    __shared__ float ldsM[KC][68];       // recon chunk: KC columns x 64 rows (+pad)

    // stage in: rows [rbase, rbase+32) of column 'lane'; coalesced across lanes
    v2f x2[NV];
#pragma unroll
    for (int i = 0; i < NV; ++i) {
        x2[i].x = A[(rbase + 2 * i + 0) * NDIM + lane];
        x2[i].y = A[(rbase + 2 * i + 1) * NDIM + lane];
    }

    float alpha = 0.0f;   // FULL column self-dot (identical on both halves)

#pragma unroll 1
    for (int sweep = 0; sweep < MAXSWEEPS; ++sweep) {
        // refresh self-dot: half-partials combined in fixed order
        v2f r0 = {0.f, 0.f}, r1 = {0.f, 0.f};
#pragma unroll
        for (int i = 0; i < NV; i += 2) {
            r0 = pk_fma(x2[i],     x2[i],     r0);
            r1 = pk_fma(x2[i + 1], x2[i + 1], r1);
        }
        ldsG[0][(h << 6) + lane] = (r0.x + r0.y) + (r1.x + r1.y);
        __syncthreads();
        alpha = ldsG[0][lane] + ldsG[0][NDIM + lane];   // canonical order

        bool any_big = false;   // per-lane; identical across halves
#pragma unroll 1
        for (int mi = 1; mi < NDIM; ++mi) {
            const int m    = (sweep & 1) ? (NDIM - mi) : mi;  // alternate direction
            const int pidx = (lane ^ m) << 2;

            // partner HALF-column: 32 bpermutes; y2 stays LIVE (fits in regs)
            v2f y2[NV];
#pragma unroll
            for (int i = 0; i < NV; ++i) {
                y2[i].x = bpermf(pidx, x2[i].x);
                y2[i].y = bpermf(pidx, x2[i].y);
            }

            // half cross-dot; same product order on both lanes of a pair ->
            // bitwise-same partial on lane p and lane q
            v2f g0 = {0.f, 0.f}, g1 = {0.f, 0.f};
#pragma unroll
            for (int i = 0; i < NV; i += 2) {
                g0 = pk_fma(x2[i],     y2[i],     g0);
                g1 = pk_fma(x2[i + 1], y2[i + 1], g1);
            }
            const float gh = (g0.x + g0.y) + (g1.x + g1.y);

            const float aex = bpermf(pidx, alpha);   // partner alpha (full)

            // cross-wave combine: double-buffered slot, ONE barrier/rotation
            ldsG[mi & 1][(h << 6) + lane] = gh;
            __syncthreads();
            const float gamma = ldsG[mi & 1][lane] + ldsG[mi & 1][NDIM + lane];

            const bool  is_p = lane < (lane ^ m);
            const float aa = is_p ? alpha : aex;  // alpha (p's self-dot)
            const float bb = is_p ? aex : alpha;  // beta  (q's self-dot)

            // convergence detector ONLY (rel 3.2e-5 > fp32 dot noise)
            any_big = any_big || ((gamma * gamma) > (1e-9f * aa * bb));

            // division-free symmetric Schur; identical on both halves and both
            // pair lanes (gamma, aa, bb all bitwise-shared)
            const bool  rot = (gamma != 0.0f);
            const float w   = 2.0f * gamma;
            const float d   = bb - aa;
            const float den = fabsf(d) + __builtin_amdgcn_sqrtf(fmaf(w, w, fmaf(d, d, 1e-35f)));
            const float t   = ((d >= 0.0f) ? w : -w) * __builtin_amdgcn_rcpf(den);
            const float cc  = __builtin_amdgcn_rsqf(fmaf(t, t, 1.0f));
            const float ss  = t * cc;

            const float sgn = is_p ? -1.0f : 1.0f;  // p: x' = c x - s y ; q: x' = c x + s y
            const float c_r = rot ? cc : 1.0f;
            const float s_r = rot ? sgn * ss : 0.0f;
            const float tg  = rot ? sgn * t * gamma : 0.0f;

            v2f c2; c2.x = c_r; c2.y = c_r;
            v2f s2; s2.x = s_r; s2.y = s_r;
#pragma unroll
            for (int i = 0; i < NV; ++i)
                x2[i] = pk_fma(c2, x2[i], pk_mul(s2, y2[i]));
            alpha += tg;                            // alpha' = alpha -/+ t*gamma
        }
        if (__ballot(any_big) == 0ull) break;   // uniform across both waves
    }

    // eigenvalue & weight: lambda = ||m||, w = log(lambda + 1e-9) / lambda^2
    v2f f0 = {0.f, 0.f}, f1 = {0.f, 0.f};
#pragma unroll
    for (int i = 0; i < NV; i += 2) {
        f0 = pk_fma(x2[i],     x2[i],     f0);
        f1 = pk_fma(x2[i + 1], x2[i + 1], f1);
    }
    ldsG[0][(h << 6) + lane] = (f0.x + f0.y) + (f1.x + f1.y);
    __syncthreads();
    const float af = ldsG[0][lane] + ldsG[0][NDIM + lane];
    if (h == 0)
        ldsW[lane] = logf(__builtin_amdgcn_sqrtf(af) + 1e-9f) / af;
    // ldsW visibility: fenced by the recon loop's first __syncthreads

    // O[rbase:rbase+32, lane] = sum_k (w_k * m_{lane,k}) * m_{rbase:,k}
    v2f acc2[NV];
#pragma unroll
    for (int i = 0; i < NV; ++i) { acc2[i].x = 0.f; acc2[i].y = 0.f; }

#pragma unroll 1
    for (int c = 0; c < NDIM; c += KC) {
        __syncthreads();   // prev chunk fully read (and ldsW visible on c==0)
        if (lane >= c && lane < c + KC) {
            float4* rowp = (float4*)&ldsM[lane - c][rbase];   // this wave's 32 rows
#pragma unroll
            for (int t4 = 0; t4 < 8; ++t4)
                rowp[t4] = make_float4(x2[2 * t4].x, x2[2 * t4].y,
                                       x2[2 * t4 + 1].x, x2[2 * t4 + 1].y);
        }
        __syncthreads();
#pragma unroll 1
        for (int kk = 0; kk < KC; ++kk) {
            const float wk  = ldsW[c + kk];             // broadcast
            const float mlk = ldsM[kk][lane];           // consecutive -> conflict-free
            const float zk  = wk * mlk;
            v2f zk2; zk2.x = zk; zk2.y = zk;
            const float4* rowk = (const float4*)&ldsM[kk][rbase];
#pragma unroll
            for (int t4 = 0; t4 < 8; ++t4) {
                const float4 v = rowk[t4];              // broadcast float4
                v2f lo; lo.x = v.x; lo.y = v.y;
                v2f hi; hi.x = v.z; hi.y = v.w;
                acc2[2 * t4]     = pk_fma(zk2, lo, acc2[2 * t4]);
                acc2[2 * t4 + 1] = pk_fma(zk2, hi, acc2[2 * t4 + 1]);
            }
        }
    }

#pragma unroll
    for (int i = 0; i < NV; ++i) {
        O[(rbase + 2 * i + 0) * NDIM + lane] = acc2[i].x;   // coalesced across lanes
        O[(rbase + 2 * i + 1) * NDIM + lane] = acc2[i].y;
    }
}

extern "C" void kernel_launch(void* const* d_in, const int* in_sizes, int n_in,
                              void* d_out, int out_size, void* d_ws, size_t ws_size,
                              hipStream_t stream)
{
    const float* in  = (const float*)d_in[0];
    float*       out = (float*)d_out;
    const int nmat = out_size / (NDIM * NDIM);   // 256*32 = 8192
    hipLaunchKernelGGL(logeig_jacobi_kernel, dim3(nmat), dim3(128), 0, stream, in, out);
}